// Round 1
// baseline (29090.411 us; speedup 1.0000x reference)
//
#include <hip/hip_runtime.h>
#include <stdint.h>
#include <limits.h>

// Problem constants (match reference)
#define T_STEPS 100
#define BSZ 512
#define HL 1024
#define HC 256
#define EMB 256
#define VOC 32000
#define NCHUNK 250           // VOC / 128

typedef __attribute__((ext_vector_type(8))) short short8;
typedef __attribute__((ext_vector_type(4))) float f32x4;
typedef __attribute__((ext_vector_type(4))) unsigned short u16x4;
#define MFMA16(a, b, c) __builtin_amdgcn_mfma_f32_16x16x32_bf16(a, b, c, 0, 0, 0)

// 6-term product of triple-split operands: residual ~2^-24 (fp32-class)
#define ACC6(acc, ah, am, al, bh, bm, bl) \
  { acc = MFMA16(ah, bh, acc); acc = MFMA16(ah, bm, acc); acc = MFMA16(am, bh, acc); \
    acc = MFMA16(ah, bl, acc); acc = MFMA16(am, bm, acc); acc = MFMA16(al, bh, acc); }

// ---------------- threefry2x32 (JAX-exact, partitionable variant verified R1) ----------------
__device__ __forceinline__ void threefry2x32(uint32_t k0, uint32_t k1,
                                             uint32_t x0, uint32_t x1,
                                             uint32_t& o0, uint32_t& o1) {
  uint32_t ks2 = k0 ^ k1 ^ 0x1BD11BDAu;
  x0 += k0; x1 += k1;
#define TF_R(x, r) (((x) << (r)) | ((x) >> (32 - (r))))
#define TF_RND(r) { x0 += x1; x1 = TF_R(x1, r); x1 ^= x0; }
  TF_RND(13) TF_RND(15) TF_RND(26) TF_RND(6)
  x0 += k1; x1 += ks2 + 1u;
  TF_RND(17) TF_RND(29) TF_RND(16) TF_RND(24)
  x0 += ks2; x1 += k0 + 2u;
  TF_RND(13) TF_RND(15) TF_RND(26) TF_RND(6)
  x0 += k0; x1 += k1 + 3u;
  TF_RND(17) TF_RND(29) TF_RND(16) TF_RND(24)
  x0 += k1; x1 += ks2 + 4u;
  TF_RND(13) TF_RND(15) TF_RND(26) TF_RND(6)
  x0 += ks2; x1 += k0 + 5u;
#undef TF_RND
#undef TF_R
  o0 = x0; o1 = x1;
}

__device__ __forceinline__ float gumbel_from_u32(uint32_t bits) {
  float f = __uint_as_float((bits >> 9) | 0x3f800000u) - 1.0f;
  f = fmaxf(f, 1.17549435e-38f);
  return -logf(-logf(f));
}

__device__ __forceinline__ float read_temp(const int* p) {
  int v = *p;
  if (v >= -(1 << 24) && v <= (1 << 24)) return (float)v;
  return __int_as_float(v);
}

__device__ __forceinline__ unsigned short f2bf(float x) {
  uint32_t u = __float_as_uint(x);
  u += 0x7fffu + ((u >> 16) & 1u);
  return (unsigned short)(u >> 16);
}
__device__ __forceinline__ float bf2f(unsigned short h) {
  return __uint_as_float(((uint32_t)h) << 16);
}
__device__ __forceinline__ void split3(float x, unsigned short& h,
                                       unsigned short& m, unsigned short& l) {
  h = f2bf(x);
  float r = x - bf2f(h);     // exact
  m = f2bf(r);
  r = r - bf2f(m);           // exact
  l = f2bf(r);
}

// ---------------- fp32 -> bf16 triple split (once per launch: w_ih, emb) ----------------
__global__ __launch_bounds__(256) void k_split3(const float* __restrict__ src,
                                                unsigned short* __restrict__ hi,
                                                unsigned short* __restrict__ mid,
                                                unsigned short* __restrict__ lo,
                                                int n4) {
  int i = blockIdx.x * 256 + threadIdx.x;
  if (i >= n4) return;
  float4 v = ((const float4*)src)[i];
  float vv[4] = {v.x, v.y, v.z, v.w};
  u16x4 h, m, l;
#pragma unroll
  for (int j = 0; j < 4; j++) {
    unsigned short a, b, c;
    split3(vv[j], a, b, c);
    h[j] = a; m[j] = b; l[j] = c;
  }
  ((u16x4*)hi)[i] = h;
  ((u16x4*)mid)[i] = m;
  ((u16x4*)lo)[i] = l;
}

// ---------------- init: keys, token copy, H0 copy ----------------
__global__ __launch_bounds__(256) void k_init(const float* __restrict__ lang_h0,
                                              const int* __restrict__ inpt0,
                                              uint32_t* __restrict__ keys,
                                              int* __restrict__ cur_tok,
                                              float* __restrict__ H0) {
  int idx = blockIdx.x * 256 + threadIdx.x;
  if (idx < T_STEPS) {
    uint32_t o0, o1;
    threefry2x32(0u, 1u, 0u, (uint32_t)idx, o0, o1);
    keys[2 * idx] = o0; keys[2 * idx + 1] = o1;
  }
  if (idx < BSZ) cur_tok[idx] = inpt0[idx];
  if (idx < BSZ * HL) H0[idx] = lang_h0[idx];
}

// ---------------- GI = [emb[tok],ctx] @ w_ih^T + b_ih, 6-term MFMA ----------------
// grid (3072/64=48, 512/64=8), 256 thr = 4 waves. Wave: 16 b x 64 n.
// A-side gathered fp32 and triple-split in-register; B from pre-split wih.
__global__ __launch_bounds__(256) void k_gi(
    const float* __restrict__ emb, const float* __restrict__ ctx,
    const int* __restrict__ tok,
    const unsigned short* __restrict__ wih_h, const unsigned short* __restrict__ wih_m,
    const unsigned short* __restrict__ wih_l,
    const float* __restrict__ b_ih, float* __restrict__ GI) {
  int tid = threadIdx.x;
  int wave = tid >> 6, lane = tid & 63;
  int ml = lane & 15, quad = lane >> 4;
  int n0 = blockIdx.x * 64;
  int bA = blockIdx.y * 64 + wave * 16 + ml;
  int myt = tok[bA];
  f32x4 acc[4];
#pragma unroll
  for (int tn = 0; tn < 4; tn++) acc[tn] = (f32x4){0.f, 0.f, 0.f, 0.f};

  for (int k0 = 0; k0 < 512; k0 += 32) {
    int k = k0 + quad * 8;
    const float* src = (k < 256) ? (emb + (size_t)myt * 256 + k)
                                 : (ctx + (size_t)bA * 256 + (k - 256));
    float4 x0 = *(const float4*)src;
    float4 x1 = *(const float4*)(src + 4);
    float xf[8] = {x0.x, x0.y, x0.z, x0.w, x1.x, x1.y, x1.z, x1.w};
    short8 ah, am_, al;
#pragma unroll
    for (int j = 0; j < 8; j++) {
      unsigned short a, b, c;
      split3(xf[j], a, b, c);
      ah[j] = (short)a; am_[j] = (short)b; al[j] = (short)c;
    }
#pragma unroll
    for (int tn = 0; tn < 4; tn++) {
      int n = n0 + tn * 16 + ml;
      size_t off = (size_t)n * 512 + k;
      short8 bh = *(const short8*)(wih_h + off);
      short8 bm = *(const short8*)(wih_m + off);
      short8 bl = *(const short8*)(wih_l + off);
      ACC6(acc[tn], ah, am_, al, bh, bm, bl);
    }
  }
  // C layout: col = lane&15 (n), row = quad*4+reg (b)
  int brow = blockIdx.y * 64 + wave * 16 + quad * 4;
#pragma unroll
  for (int tn = 0; tn < 4; tn++) {
    int n = n0 + tn * 16 + ml;
    float bias = b_ih[n];
#pragma unroll
    for (int reg = 0; reg < 4; reg++)
      GI[(size_t)(brow + reg) * 3072 + n] = acc[tn][reg] + bias;
  }
}

// ---------------- GRU: GH (fp32 vector) + GI add + pointwise, writes Hout ----------------
// grid (1024/32=32, 512/64=8), 128 thr. Block: 64 b x 32 i x 3 gates.
__global__ __launch_bounds__(128) void k_gru(const float* __restrict__ Hin,
                                             const float* __restrict__ w_hh,
                                             const float* __restrict__ b_hh,
                                             const float* __restrict__ GI,
                                             float* __restrict__ Hout) {
  __shared__ __align__(16) float Ah[32][68];
  __shared__ __align__(16) float Wr[32][34];
  __shared__ __align__(16) float Wz[32][34];
  __shared__ __align__(16) float Wn[32][34];
  int tid = threadIdx.x;
  int ti = tid & 15;
  int tb = tid >> 4;
  int b0 = blockIdx.y * 64, i0 = blockIdx.x * 32;
  int sr = tid >> 3;          // 0..15
  int kq = (tid & 7) * 4;
  float acc[3][8][2] = {};

  for (int k0 = 0; k0 < 1024; k0 += 32) {
#pragma unroll
    for (int i = 0; i < 4; i++) {
      int r = sr + 16 * i;
      float4 h4 = *(const float4*)&Hin[(size_t)(b0 + r) * 1024 + k0 + kq];
      Ah[kq + 0][r] = h4.x; Ah[kq + 1][r] = h4.y; Ah[kq + 2][r] = h4.z; Ah[kq + 3][r] = h4.w;
    }
#pragma unroll
    for (int g = 0; g < 3; g++) {
      float* Wg = (g == 0 ? &Wr[0][0] : g == 1 ? &Wz[0][0] : &Wn[0][0]);
      const float* src = w_hh + (size_t)(g * 1024 + i0) * 1024;
#pragma unroll
      for (int i = 0; i < 2; i++) {
        int r = sr + 16 * i;
        float4 w4 = *(const float4*)&src[(size_t)r * 1024 + k0 + kq];
        Wg[(kq + 0) * 34 + r] = w4.x; Wg[(kq + 1) * 34 + r] = w4.y;
        Wg[(kq + 2) * 34 + r] = w4.z; Wg[(kq + 3) * 34 + r] = w4.w;
      }
    }
    __syncthreads();
#pragma unroll
    for (int kk = 0; kk < 32; kk++) {
      float4 a0 = *(float4*)&Ah[kk][tb * 8];
      float4 a1 = *(float4*)&Ah[kk][tb * 8 + 4];
      float av[8] = {a0.x, a0.y, a0.z, a0.w, a1.x, a1.y, a1.z, a1.w};
      float2 wr2 = *(float2*)&Wr[kk][ti * 2];
      float2 wz2 = *(float2*)&Wz[kk][ti * 2];
      float2 wn2 = *(float2*)&Wn[kk][ti * 2];
      float wv0[2] = {wr2.x, wr2.y};
      float wv1[2] = {wz2.x, wz2.y};
      float wv2[2] = {wn2.x, wn2.y};
#pragma unroll
      for (int bb = 0; bb < 8; bb++)
#pragma unroll
        for (int j = 0; j < 2; j++) {
          acc[0][bb][j] += av[bb] * wv0[j];
          acc[1][bb][j] += av[bb] * wv1[j];
          acc[2][bb][j] += av[bb] * wv2[j];
        }
    }
    __syncthreads();
  }
  int i = i0 + ti * 2;
  float2 bhr = *(const float2*)&b_hh[i];
  float2 bhz = *(const float2*)&b_hh[1024 + i];
  float2 bhn = *(const float2*)&b_hh[2048 + i];
  float bhrv[2] = {bhr.x, bhr.y}, bhzv[2] = {bhz.x, bhz.y}, bhnv[2] = {bhn.x, bhn.y};
#pragma unroll
  for (int bb = 0; bb < 8; bb++) {
    int b = b0 + tb * 8 + bb;
    float2 gir = *(const float2*)&GI[(size_t)b * 3072 + i];
    float2 giz = *(const float2*)&GI[(size_t)b * 3072 + 1024 + i];
    float2 gin = *(const float2*)&GI[(size_t)b * 3072 + 2048 + i];
    float2 h2 = *(const float2*)&Hin[(size_t)b * 1024 + i];
    float girv[2] = {gir.x, gir.y}, gizv[2] = {giz.x, giz.y}, ginv[2] = {gin.x, gin.y};
    float hv[2] = {h2.x, h2.y}, ov[2];
#pragma unroll
    for (int j = 0; j < 2; j++) {
      float r = 1.0f / (1.0f + expf(-(girv[j] + acc[0][bb][j] + bhrv[j])));
      float z = 1.0f / (1.0f + expf(-(gizv[j] + acc[1][bb][j] + bhzv[j])));
      float n = tanhf(ginv[j] + r * (acc[2][bb][j] + bhnv[j]));
      ov[j] = (1.0f - z) * n + z * hv[j];
    }
    float2 o; o.x = ov[0]; o.y = ov[1];
    *(float2*)&Hout[(size_t)b * 1024 + i] = o;
  }
}

// ---------------- dec GEMM (fp32) + fused triple-split output ----------------
// grid (256/64=4, 512/16=32), 256 thr. Block: 16 b x 64 cols, K=1024.
__global__ __launch_bounds__(256) void k_dec(const float* __restrict__ H,
                                             const float* __restrict__ dec_W,
                                             const float* __restrict__ dec_b,
                                             unsigned short* __restrict__ dh,
                                             unsigned short* __restrict__ dm,
                                             unsigned short* __restrict__ dl) {
  __shared__ __align__(16) float As[32][20];
  __shared__ __align__(16) float Ws[32][68];
  int tid = threadIdx.x;
  int tb = tid >> 4;          // 0..15 = b row
  int tv = tid & 15;          // 4 cols: tv*4
  int col0 = blockIdx.x * 64, row0 = blockIdx.y * 16;
  int srw = tid >> 3;         // 0..31
  int kq = (tid & 7) * 4;
  float acc[4] = {};
  for (int k0 = 0; k0 < 1024; k0 += 32) {
    if (srw < 16) {           // As: 16 rows x 32 k
      float4 a4 = *(const float4*)&H[(size_t)(row0 + srw) * 1024 + k0 + kq];
      As[kq + 0][srw] = a4.x; As[kq + 1][srw] = a4.y; As[kq + 2][srw] = a4.z; As[kq + 3][srw] = a4.w;
    }
    // Ws: 64 rows x 32 k — rows srw and srw+32
#pragma unroll
    for (int i = 0; i < 2; i++) {
      int r = srw + 32 * i;
      float4 w4 = *(const float4*)&dec_W[(size_t)(col0 + r) * 1024 + k0 + kq];
      Ws[kq + 0][r] = w4.x; Ws[kq + 1][r] = w4.y;
      Ws[kq + 2][r] = w4.z; Ws[kq + 3][r] = w4.w;
    }
    __syncthreads();
#pragma unroll
    for (int kk = 0; kk < 32; kk++) {
      float a = As[kk][tb];
      float4 w = *(float4*)&Ws[kk][tv * 4];
      float wv[4] = {w.x, w.y, w.z, w.w};
#pragma unroll
      for (int j = 0; j < 4; j++) acc[j] += a * wv[j];
    }
    __syncthreads();
  }
  int col = col0 + tv * 4;
  float4 b4 = *(const float4*)&dec_b[col];
  float bv[4] = {b4.x, b4.y, b4.z, b4.w};
  u16x4 h, m, l;
#pragma unroll
  for (int j = 0; j < 4; j++) {
    unsigned short a, b, c;
    split3(acc[j] + bv[j], a, b, c);
    h[j] = a; m[j] = b; l[j] = c;
  }
  size_t o = (size_t)(row0 + tb) * 256 + col;
  *(u16x4*)(dh + o) = h;
  *(u16x4*)(dm + o) = m;
  *(u16x4*)(dl + o) = l;
}

// ---------------- logits 6-term MFMA + gumbel + per-chunk argmax ----------------
// grid (250, 4), 256 thr = 4 waves. Block: 128 b x 128 v; wave: 32 b (2 m-tiles) x 128 v.
// B-side (emb) PRE-SPLIT in global (ebh/ebm/ebl); staging is a pure bf16 copy into
// padded LDS ([128][40] shorts, conflict-free on ds_read_b128).
__global__ __launch_bounds__(256) void k_logits(const unsigned short* __restrict__ dh,
                                                const unsigned short* __restrict__ dm,
                                                const unsigned short* __restrict__ dl,
                                                const unsigned short* __restrict__ ebh,
                                                const unsigned short* __restrict__ ebm,
                                                const unsigned short* __restrict__ ebl,
                                                const uint32_t* __restrict__ keys,
                                                int t,
                                                const int* __restrict__ temp_ptr,
                                                float* __restrict__ pval,
                                                int* __restrict__ pidx) {
  __shared__ __align__(16) unsigned short Eh[128 * 40];
  __shared__ __align__(16) unsigned short Em[128 * 40];
  __shared__ __align__(16) unsigned short El[128 * 40];
  int tid = threadIdx.x;
  int wave = tid >> 6, lane = tid & 63;
  int ml = lane & 15, quad = lane >> 4;
  int c = blockIdx.x;
  int v0 = c * 128;
  int b0 = blockIdx.y * 128;
  f32x4 acc[2][8];
#pragma unroll
  for (int mi = 0; mi < 2; mi++)
#pragma unroll
    for (int tv = 0; tv < 8; tv++) acc[mi][tv] = (f32x4){0.f, 0.f, 0.f, 0.f};

  for (int k0 = 0; k0 < 256; k0 += 32) {
    __syncthreads();
    // stage pre-split emb tile [128 v][32 k] — pure copy, no split arithmetic
#pragma unroll
    for (int i = 0; i < 4; i++) {
      int idx4 = tid + i * 256;          // 0..1023 u16x4 slots
      int v = idx4 >> 3;
      int k4 = (idx4 & 7) * 4;
      size_t go = (size_t)(v0 + v) * 256 + k0 + k4;
      *(u16x4*)&Eh[v * 40 + k4] = *(const u16x4*)(ebh + go);
      *(u16x4*)&Em[v * 40 + k4] = *(const u16x4*)(ebm + go);
      *(u16x4*)&El[v * 40 + k4] = *(const u16x4*)(ebl + go);
    }
    __syncthreads();
    // A fragments (dec triple-split, global; L2-resident 786 KB)
    short8 ah[2], am_[2], al[2];
#pragma unroll
    for (int mi = 0; mi < 2; mi++) {
      int brow = b0 + wave * 32 + mi * 16 + ml;
      size_t off = (size_t)brow * 256 + k0 + quad * 8;
      ah[mi] = *(const short8*)(dh + off);
      am_[mi] = *(const short8*)(dm + off);
      al[mi] = *(const short8*)(dl + off);
    }
#pragma unroll
    for (int tv = 0; tv < 8; tv++) {
      int lo = (tv * 16 + ml) * 40 + quad * 8;
      short8 bh = *(const short8*)&Eh[lo];
      short8 bm = *(const short8*)&Em[lo];
      short8 bl = *(const short8*)&El[lo];
#pragma unroll
      for (int mi = 0; mi < 2; mi++)
        ACC6(acc[mi][tv], ah[mi], am_[mi], al[mi], bh, bm, bl);
    }
  }
  float temp = read_temp(temp_ptr);
  uint32_t kk0 = keys[2 * t], kk1 = keys[2 * t + 1];
#pragma unroll
  for (int mi = 0; mi < 2; mi++) {
    float best[4];
    int bidx[4];
#pragma unroll
    for (int reg = 0; reg < 4; reg++) { best[reg] = -3.402823466e38f; bidx[reg] = INT_MAX; }
    // C layout: col (v) = lane&15, row (b) = quad*4+reg
#pragma unroll
    for (int tv = 0; tv < 8; tv++) {
      int v = v0 + tv * 16 + ml;
#pragma unroll
      for (int reg = 0; reg < 4; reg++) {
        int b = b0 + wave * 32 + mi * 16 + quad * 4 + reg;
        uint32_t o0, o1;
        threefry2x32(kk0, kk1, 0u, (uint32_t)(b * VOC + v), o0, o1);
        float s = acc[mi][tv][reg] / temp + gumbel_from_u32(o0 ^ o1);
        if (s > best[reg]) { best[reg] = s; bidx[reg] = v; }
      }
    }
#pragma unroll
    for (int off = 1; off < 16; off <<= 1) {
#pragma unroll
      for (int reg = 0; reg < 4; reg++) {
        float ov = __shfl_xor(best[reg], off, 64);
        int oi = __shfl_xor(bidx[reg], off, 64);
        if (ov > best[reg] || (ov == best[reg] && oi < bidx[reg])) {
          best[reg] = ov; bidx[reg] = oi;
        }
      }
    }
    if (ml == 0) {
#pragma unroll
      for (int reg = 0; reg < 4; reg++) {
        int b = b0 + wave * 32 + mi * 16 + quad * 4 + reg;
        pval[(size_t)b * NCHUNK + c] = best[reg];
        pidx[(size_t)b * NCHUNK + c] = bidx[reg];
      }
    }
  }
}

// ---------------- final argmax over chunks ----------------
__global__ __launch_bounds__(256) void k_argmax_final(const float* __restrict__ pval,
                                                      const int* __restrict__ pidx,
                                                      int* __restrict__ cur_tok,
                                                      float* __restrict__ outs_t) {
  __shared__ float sv[256];
  __shared__ int si[256];
  int b = blockIdx.x, tid = threadIdx.x;
  float bv = -3.402823466e38f;
  int bi = INT_MAX;
  for (int c = tid; c < NCHUNK; c += 256) {
    float v = pval[(size_t)b * NCHUNK + c];
    int i2 = pidx[(size_t)b * NCHUNK + c];
    if (v > bv || (v == bv && i2 < bi)) { bv = v; bi = i2; }
  }
  sv[tid] = bv; si[tid] = bi;
  __syncthreads();
  for (int s = 128; s > 0; s >>= 1) {
    if (tid < s) {
      float v = sv[tid + s]; int i2 = si[tid + s];
      if (v > sv[tid] || (v == sv[tid] && i2 < si[tid])) { sv[tid] = v; si[tid] = i2; }
    }
    __syncthreads();
  }
  if (tid == 0) { cur_tok[b] = si[0]; outs_t[b] = (float)si[0]; }
}

extern "C" void kernel_launch(void* const* d_in, const int* in_sizes, int n_in,
                              void* d_out, int out_size, void* d_ws, size_t ws_size,
                              hipStream_t stream) {
  const float* lang_h0 = (const float*)d_in[0];
  const float* ctx_h   = (const float*)d_in[1];
  const float* emb     = (const float*)d_in[2];
  const float* dec_W   = (const float*)d_in[3];
  const float* dec_b   = (const float*)d_in[4];
  const float* w_ih    = (const float*)d_in[5];
  const float* w_hh    = (const float*)d_in[6];
  const float* b_ih    = (const float*)d_in[7];
  const float* b_hh    = (const float*)d_in[8];
  const int*   inpt0   = (const int*)d_in[9];
  const int*   temp_p  = (const int*)d_in[10];

  float* out = (float*)d_out;
  float* outs = out;                           // [100][512] token ids as f32
  float* Hbase = out + (size_t)T_STEPS * BSZ;  // [102][512][1024]

  uint8_t* ws = (uint8_t*)d_ws;
  uint32_t* keys = (uint32_t*)ws;                               // 800 B
  int* cur_tok = (int*)(ws + 4096);                             // 2 KB
  unsigned short* dh = (unsigned short*)(ws + 8192);            // 512x256 bf16 x3
  unsigned short* dm = dh + (size_t)BSZ * EMB;
  unsigned short* dl = dm + (size_t)BSZ * EMB;
  float* pval = (float*)(dl + (size_t)BSZ * EMB);               // 512x250
  int* pidx = (int*)(pval + (size_t)BSZ * NCHUNK);
  float* GI = (float*)(pidx + (size_t)BSZ * NCHUNK);            // 512x3072 f32 (6 MB)
  unsigned short* wih_h = (unsigned short*)(GI + (size_t)BSZ * 3 * HL);  // 3072x512 x3
  unsigned short* wih_m = wih_h + (size_t)3 * HL * 512;
  unsigned short* wih_l = wih_m + (size_t)3 * HL * 512;
  unsigned short* ebh = wih_l + (size_t)3 * HL * 512;           // 32000x256 bf16 x3 (49 MB)
  unsigned short* ebm = ebh + (size_t)VOC * EMB;
  unsigned short* ebl = ebm + (size_t)VOC * EMB;
  // total ws use ~66 MB

  k_split3<<<(3 * HL * 512 / 4 + 255) / 256, 256, 0, stream>>>(w_ih, wih_h, wih_m, wih_l,
                                                               3 * HL * 512 / 4);
  k_split3<<<(VOC * EMB / 4 + 255) / 256, 256, 0, stream>>>(emb, ebh, ebm, ebl,
                                                            VOC * EMB / 4);
  k_init<<<(BSZ * HL) / 256, 256, 0, stream>>>(lang_h0, inpt0, keys, cur_tok, Hbase);

  for (int t = 0; t <= T_STEPS; t++) {
    const float* Hin = Hbase + (size_t)t * BSZ * HL;
    float* Hout = Hbase + (size_t)(t + 1) * BSZ * HL;
    k_gi<<<dim3(48, 8), 256, 0, stream>>>(emb, ctx_h, cur_tok,
                                          wih_h, wih_m, wih_l, b_ih, GI);
    k_gru<<<dim3(32, 8), 128, 0, stream>>>(Hin, w_hh, b_hh, GI, Hout);
    if (t == T_STEPS) break;                   // extra writer step: no sampling
    k_dec<<<dim3(4, 32), 256, 0, stream>>>(Hout, dec_W, dec_b, dh, dm, dl);
    k_logits<<<dim3(NCHUNK, 4), 256, 0, stream>>>(dh, dm, dl, ebh, ebm, ebl, keys, t,
                                                  temp_p, pval, pidx);
    k_argmax_final<<<BSZ, 256, 0, stream>>>(pval, pidx, cur_tok, outs + (size_t)t * BSZ);
  }
}